// Round 4
// baseline (1352.207 us; speedup 1.0000x reference)
//
#include <hip/hip_runtime.h>
#include <hip/hip_fp16.h>

#define IN_F 256
#define OUT_F 128
#define RPB 128         // rows per bucket
#define MAXB 1024       // max buckets supported by LDS arrays (n_nodes <= 131072)
#define CHUNK 16384     // edges per coarse_bin block

// ---------------- K1: sup(fp16) = x @ W  (fp32 accum) -----------------------
__global__ __launch_bounds__(256) void gemm_xw(const float* __restrict__ x,
                                               const float* __restrict__ w,
                                               __half* __restrict__ sup,
                                               int n_nodes) {
  __shared__ float xs[16][IN_F];
  int row0 = blockIdx.x * 16;
  const float4* xg = (const float4*)(x + (size_t)row0 * IN_F);
  float4* xsv = (float4*)&xs[0][0];
#pragma unroll
  for (int i = 0; i < 4; ++i) xsv[threadIdx.x + i * 256] = xg[threadIdx.x + i * 256];
  __syncthreads();

  int c = threadIdx.x & 127;
  int rbase = (threadIdx.x >> 7) * 8;
  float acc[8] = {0.f, 0.f, 0.f, 0.f, 0.f, 0.f, 0.f, 0.f};
  for (int k = 0; k < IN_F; k += 4) {
    float w0 = w[(k + 0) * OUT_F + c];
    float w1 = w[(k + 1) * OUT_F + c];
    float w2 = w[(k + 2) * OUT_F + c];
    float w3 = w[(k + 3) * OUT_F + c];
#pragma unroll
    for (int r = 0; r < 8; ++r) {
      float4 xv = *(const float4*)&xs[rbase + r][k];
      acc[r] = fmaf(xv.x, w0, acc[r]);
      acc[r] = fmaf(xv.y, w1, acc[r]);
      acc[r] = fmaf(xv.z, w2, acc[r]);
      acc[r] = fmaf(xv.w, w3, acc[r]);
    }
  }
#pragma unroll
  for (int r = 0; r < 8; ++r) {
    int row = row0 + rbase + r;
    if (row < n_nodes) sup[(size_t)row * OUT_F + c] = __float2half(acc[r]);
  }
}

// ---------------- bucket-level hist + scan ----------------------------------
__global__ __launch_bounds__(256) void bzero(int* __restrict__ p, int n) {
  int i = blockIdx.x * 256 + threadIdx.x;
  if (i < n) p[i] = 0;
}

__global__ __launch_bounds__(256) void bucket_hist(const int* __restrict__ erow,
                                                   int* __restrict__ bcnt, int n_edges) {
  int e = blockIdx.x * 256 + threadIdx.x;
  if (e < n_edges) atomicAdd(&bcnt[erow[e] >> 7], 1);
}

__global__ __launch_bounds__(1024) void bucket_scan(const int* __restrict__ bcnt,
                                                    int* __restrict__ bptr,
                                                    int* __restrict__ gcur, int nbuck) {
  __shared__ int sc[1024];
  int t = threadIdx.x;
  int v = (t < nbuck) ? bcnt[t] : 0;
  sc[t] = v;
  __syncthreads();
  for (int off = 1; off < 1024; off <<= 1) {
    int u = (t >= off) ? sc[t - off] : 0;
    __syncthreads();
    sc[t] += u;
    __syncthreads();
  }
  if (t < nbuck) {
    int ex = sc[t] - v;  // exclusive
    bptr[t] = ex;
    gcur[t] = ex;
  }
  if (t == 0) bptr[nbuck] = sc[1023];
}

// ---------------- coarse binning with per-block run reservation -------------
// tmp[pos] = { col | (rowlocal<<17), val_bits }, grouped by bucket.
__global__ __launch_bounds__(256) void coarse_bin(const int* __restrict__ erow,
                                                  const int* __restrict__ ecol,
                                                  const float* __restrict__ eval,
                                                  int* __restrict__ gcur,
                                                  int2* __restrict__ tmp,
                                                  int n_edges, int nbuck) {
  __shared__ int cnt[MAXB];
  __shared__ int base[MAXB];
  int t = threadIdx.x;
  for (int i = t; i < nbuck; i += 256) cnt[i] = 0;
  __syncthreads();
  int beg = blockIdx.x * CHUNK;
  int end = min(beg + CHUNK, n_edges);
  // phase a: block-local bucket histogram
  for (int e = beg + t; e < end; e += 256) atomicAdd(&cnt[erow[e] >> 7], 1);
  __syncthreads();
  // phase b: reserve runs
  for (int i = t; i < nbuck; i += 256) {
    int c = cnt[i];
    base[i] = (c > 0) ? atomicAdd(&gcur[i], c) : 0;
    cnt[i] = 0;  // reuse as local cursor
  }
  __syncthreads();
  // phase c: scatter into reserved runs (edge data L2-hot from phase a)
  for (int e = beg + t; e < end; e += 256) {
    int r = erow[e];
    int b = r >> 7;
    int pos = base[b] + atomicAdd(&cnt[b], 1);
    int2 pk;
    pk.x = ecol[e] | ((r & (RPB - 1)) << 17);
    pk.y = __float_as_int(eval[e]);
    tmp[pos] = pk;
  }
}

// ---------------- fused: in-block counting sort + gather + bias + relu ------
// one block per bucket (128 rows). pedge region is block-private and L2-hot.
__global__ __launch_bounds__(256) void fine_gather(const int* __restrict__ bptr,
                                                   const int2* __restrict__ tmp,
                                                   int2* __restrict__ pedge,
                                                   const __half* __restrict__ sup,
                                                   const float* __restrict__ bias,
                                                   float* __restrict__ out,
                                                   int n_nodes) {
  __shared__ int hist[RPB];
  __shared__ int sc[RPB];
  __shared__ int start[RPB + 1];
  __shared__ int cur[RPB];
  int b = blockIdx.x;
  int row0 = b << 7;
  int nr = min(RPB, n_nodes - row0);
  int t = threadIdx.x;
  int bbeg = bptr[b];
  int bend = bptr[b + 1];

  if (t < RPB) hist[t] = 0;
  __syncthreads();
  // pass 1: row histogram within bucket
  for (int j = bbeg + t; j < bend; j += 256) atomicAdd(&hist[tmp[j].x >> 17], 1);
  __syncthreads();
  // exclusive scan over 128 bins (Hillis-Steele on inclusive, then subtract)
  if (t < RPB) sc[t] = hist[t];
  __syncthreads();
  for (int off = 1; off < RPB; off <<= 1) {
    int u = (t < RPB && t >= off) ? sc[t - off] : 0;
    __syncthreads();
    if (t < RPB) sc[t] += u;
    __syncthreads();
  }
  if (t < RPB) {
    int st = bbeg + sc[t] - hist[t];
    start[t] = st;
    cur[t] = st;
  }
  if (t == 0) start[RPB] = bend;
  __syncthreads();
  // pass 2: scatter into row-sorted pedge (region ~33 KB, stays in this XCD's L2)
  for (int j = bbeg + t; j < bend; j += 256) {
    int2 e = tmp[j];
    int rl = e.x >> 17;
    int pos = atomicAdd(&cur[rl], 1);
    int2 pk;
    pk.x = e.x & 0x1FFFF;
    pk.y = e.y;
    pedge[pos] = pk;
  }
  __syncthreads();
  // pass 3: row-per-wave register gather, fused bias+relu
  int wave = t >> 6;
  int lane = t & 63;
  float2 bia = ((const float2*)bias)[lane];
  int rl_beg = wave * 32;
  int rl_end = min(rl_beg + 32, nr);
  for (int rl = rl_beg; rl < rl_end; ++rl) {
    int ebeg = start[rl];
    int eend = start[rl + 1];
    float ax = 0.f, ay = 0.f, bx = 0.f, by = 0.f;
    int j = ebeg;
    for (; j + 1 < eend; j += 2) {
      int2 e0 = pedge[j];
      int2 e1 = pedge[j + 1];
      __half2 s0 = ((const __half2*)(sup + (size_t)e0.x * OUT_F))[lane];
      __half2 s1 = ((const __half2*)(sup + (size_t)e1.x * OUT_F))[lane];
      float2 f0 = __half22float2(s0);
      float2 f1 = __half22float2(s1);
      float v0 = __int_as_float(e0.y);
      float v1 = __int_as_float(e1.y);
      ax = fmaf(f0.x, v0, ax);
      ay = fmaf(f0.y, v0, ay);
      bx = fmaf(f1.x, v1, bx);
      by = fmaf(f1.y, v1, by);
    }
    if (j < eend) {
      int2 e0 = pedge[j];
      __half2 s0 = ((const __half2*)(sup + (size_t)e0.x * OUT_F))[lane];
      float2 f0 = __half22float2(s0);
      float v0 = __int_as_float(e0.y);
      ax = fmaf(f0.x, v0, ax);
      ay = fmaf(f0.y, v0, ay);
    }
    float2 o;
    o.x = fmaxf(ax + bx + bia.x, 0.f);
    o.y = fmaxf(ay + by + bia.y, 0.f);
    ((float2*)(out + (size_t)(row0 + rl) * OUT_F))[lane] = o;
  }
}

// ---------------- fallback (atomic scatter) ---------------------------------
__global__ __launch_bounds__(256) void init_bias(float* __restrict__ out,
                                                 const float* __restrict__ bias,
                                                 int total) {
  int i = blockIdx.x * 256 + threadIdx.x;
  if (i < total) out[i] = bias[i & (OUT_F - 1)];
}

__global__ __launch_bounds__(256) void spmm_scatter(const int* __restrict__ erow,
                                                    const int* __restrict__ ecol,
                                                    const float* __restrict__ eval,
                                                    const __half* __restrict__ sup,
                                                    float* __restrict__ out,
                                                    int n_edges) {
  long long t = (long long)blockIdx.x * 256 + threadIdx.x;
  int e = (int)(t >> 6);
  if (e >= n_edges) return;
  int lane = (int)(t & 63);
  int r = erow[e];
  int c = ecol[e];
  float v = eval[e];
  __half2 s = ((const __half2*)(sup + (size_t)c * OUT_F))[lane];
  float2 f = __half22float2(s);
  float* orow = out + (size_t)r * OUT_F + 2 * lane;
  unsafeAtomicAdd(orow + 0, f.x * v);
  unsafeAtomicAdd(orow + 1, f.y * v);
}

__global__ __launch_bounds__(256) void relu_k(float* __restrict__ out, int total) {
  int i = blockIdx.x * 256 + threadIdx.x;
  if (i < total) out[i] = fmaxf(out[i], 0.f);
}

extern "C" void kernel_launch(void* const* d_in, const int* in_sizes, int n_in,
                              void* d_out, int out_size, void* d_ws, size_t ws_size,
                              hipStream_t stream) {
  const float* x = (const float*)d_in[0];
  const int* erow = (const int*)d_in[1];
  const int* ecol = (const int*)d_in[2];
  const float* eval = (const float*)d_in[3];
  const float* w = (const float*)d_in[4];
  const float* bias = (const float*)d_in[5];
  float* out = (float*)d_out;

  int n_nodes = in_sizes[0] / IN_F;   // 100000
  int n_edges = in_sizes[1];          // 3200000
  int total = n_nodes * OUT_F;
  int nbuck = (n_nodes + RPB - 1) >> 7;

  // ws layout
  char* p = (char*)d_ws;
  __half* sup = (__half*)p;             p += (size_t)n_nodes * OUT_F * 2;
  int2* tmp = (int2*)p;                 p += (size_t)n_edges * 8;
  int2* pedge = (int2*)p;               p += (size_t)n_edges * 8;
  int* bcnt = (int*)p;                  p += (size_t)nbuck * 4;
  int* bptr = (int*)p;                  p += (size_t)(nbuck + 1) * 4;
  int* gcur = (int*)p;                  p += (size_t)nbuck * 4;
  size_t need = (size_t)(p - (char*)d_ws);

  // K1: support = x @ W  (fp16 out)
  gemm_xw<<<(n_nodes + 15) / 16, 256, 0, stream>>>(x, w, sup, n_nodes);

  if (ws_size >= need && nbuck <= MAXB) {
    bzero<<<(nbuck + 255) / 256, 256, 0, stream>>>(bcnt, nbuck);
    bucket_hist<<<(n_edges + 255) / 256, 256, 0, stream>>>(erow, bcnt, n_edges);
    bucket_scan<<<1, 1024, 0, stream>>>(bcnt, bptr, gcur, nbuck);
    coarse_bin<<<(n_edges + CHUNK - 1) / CHUNK, 256, 0, stream>>>(erow, ecol, eval,
                                                                  gcur, tmp, n_edges,
                                                                  nbuck);
    fine_gather<<<nbuck, 256, 0, stream>>>(bptr, tmp, pedge, sup, bias, out, n_nodes);
  } else {
    init_bias<<<(total + 255) / 256, 256, 0, stream>>>(out, bias, total);
    long long threads = (long long)n_edges * 64;
    spmm_scatter<<<(int)((threads + 255) / 256), 256, 0, stream>>>(erow, ecol, eval,
                                                                   sup, out, n_edges);
    relu_k<<<(total + 255) / 256, 256, 0, stream>>>(out, total);
  }
}